// Round 1
// 910.915 us; speedup vs baseline: 2.5787x; 2.5787x over previous
//
#include <hip/hip_runtime.h>
#include <math.h>

// Problem constants
#define Bb 4
#define Ss 4096
#define Dd 1024
#define Hh 16
#define Ff 256
#define HDd 64
#define Mm (Bb*Ss)          // 16384 rows

typedef unsigned int u32;
typedef unsigned short u16;

typedef __attribute__((ext_vector_type(8))) short bf16x8;   // 8 bf16 = 4 VGPRs
typedef __attribute__((ext_vector_type(4))) float f32x4;

// ---- bf16 helpers ----
__device__ __forceinline__ float bflo(u32 u){ union{u32 i; float f;} c; c.i = u << 16; return c.f; }
__device__ __forceinline__ float bfhi(u32 u){ union{u32 i; float f;} c; c.i = u & 0xffff0000u; return c.f; }
__device__ __forceinline__ u16 f2b(float f){
  union{float f; u32 i;} c; c.f = f;
  u32 x = c.i;
  return (u16)((x + 0x7fffu + ((x >> 16) & 1u)) >> 16);   // RNE
}
__device__ __forceinline__ float softplusf(float x){
  return fmaxf(x, 0.f) + log1pf(expf(-fabsf(x)));   // jax.nn.softplus, stable
}
// fast softplus for the MFMA kv path (v_exp/v_log native; err << bf16 noise)
__device__ __forceinline__ float sfast(float x){
  return fmaxf(x, 0.f) + __logf(1.f + __expf(-fabsf(x)));
}

// ============================================================
// f32 -> bf16 elementwise (8 elems/thread, vectorized)
// ============================================================
__global__ void cvt_bf16(const float* __restrict__ in, u16* __restrict__ out, int n)
{
  int i = (blockIdx.x * 256 + threadIdx.x) * 8;
  if (i >= n) return;
  float4 a = *reinterpret_cast<const float4*>(in + i);
  float4 b = *reinterpret_cast<const float4*>(in + i + 4);
  u32 w0 = (u32)f2b(a.x) | ((u32)f2b(a.y) << 16);
  u32 w1 = (u32)f2b(a.z) | ((u32)f2b(a.w) << 16);
  u32 w2 = (u32)f2b(b.x) | ((u32)f2b(b.y) << 16);
  u32 w3 = (u32)f2b(b.z) | ((u32)f2b(b.w) << 16);
  *reinterpret_cast<uint4*>(out + i) = make_uint4(w0, w1, w2, w3);
}

// ============================================================
// zero-fill (ws is re-poisoned 0xAA each call)
// ============================================================
__global__ void zero_f32(float* __restrict__ p, int n)
{
  int i = blockIdx.x * 256 + threadIdx.x;
  if (i < n) p[i] = 0.f;
}

// ============================================================
// MFMA GEMM: C[M,N] = A[M,K](bf16) * W[N,K]^T(bf16) + bias
// OT = u16 (bf16 store) or float (f32 store).
// BROW: bias indexed by row m (for the V^T gemm) instead of col n.
// 128x128 tile, BK=32, 4 waves (2x2 of 64x64).
// Verified layouts (m89/m91/m120): A[m=lane&15][k=quad*8+j],
// B[k=quad*8+j][n=lane&15], D[row=quad*4+r][col=lane&15].
// ============================================================
template<typename OT, bool BROW>
__global__ __launch_bounds__(256, 2) void mfma_gemm_bt(
    const u16* __restrict__ A, const u16* __restrict__ W,
    const float* __restrict__ bias, OT* __restrict__ C,
    int M, int N, int K)
{
  // rows of 32 bf16 + 8 pad = 40 u16 (80 B): frag-read banks 2-way (free)
  __shared__ __align__(16) u16 As[128 * 40];
  __shared__ __align__(16) u16 Bs[128 * 40];

  const int tid = threadIdx.x;
  const int wave = tid >> 6, lane = tid & 63;
  const int quad = lane >> 4, lm = lane & 15;
  const int wm = (wave >> 1) * 64, wn = (wave & 1) * 64;
  const int m0 = blockIdx.x * 128, n0 = blockIdx.y * 128;

  f32x4 acc[4][4] = {};   // zero-init

  for (int k0 = 0; k0 < K; k0 += 32) {
#pragma unroll
    for (int i = 0; i < 2; i++) {
      int slot = tid + 256 * i;          // 512 slots: 128 rows x 4 col-groups
      int r = slot >> 2, cg = slot & 3;
      *reinterpret_cast<uint4*>(&As[r * 40 + cg * 8]) =
          *reinterpret_cast<const uint4*>(A + (size_t)(m0 + r) * K + k0 + cg * 8);
      *reinterpret_cast<uint4*>(&Bs[r * 40 + cg * 8]) =
          *reinterpret_cast<const uint4*>(W + (size_t)(n0 + r) * K + k0 + cg * 8);
    }
    __syncthreads();

    bf16x8 af[4], bf[4];
#pragma unroll
    for (int mi = 0; mi < 4; mi++)
      af[mi] = *reinterpret_cast<const bf16x8*>(&As[(wm + mi * 16 + lm) * 40 + quad * 8]);
#pragma unroll
    for (int ni = 0; ni < 4; ni++)
      bf[ni] = *reinterpret_cast<const bf16x8*>(&Bs[(wn + ni * 16 + lm) * 40 + quad * 8]);
#pragma unroll
    for (int mi = 0; mi < 4; mi++)
#pragma unroll
      for (int ni = 0; ni < 4; ni++)
        acc[mi][ni] = __builtin_amdgcn_mfma_f32_16x16x32_bf16(af[mi], bf[ni], acc[mi][ni], 0, 0, 0);
    __syncthreads();
  }

  // epilogue: lane l, reg r -> C[m0+wm+mi*16+quad*4+r][n0+wn+ni*16+lm]
#pragma unroll
  for (int mi = 0; mi < 4; mi++)
#pragma unroll
    for (int ni = 0; ni < 4; ni++) {
      const int n = n0 + wn + ni * 16 + lm;
      const float bvn = BROW ? 0.f : bias[n];
#pragma unroll
      for (int r = 0; r < 4; r++) {
        const int m = m0 + wm + mi * 16 + quad * 4 + r;
        const float val = acc[mi][ni][r] + (BROW ? bias[m] : bvn);
        if constexpr (sizeof(OT) == 2) ((u16*)C)[(size_t)m * N + n] = f2b(val);
        else                           ((float*)C)[(size_t)m * N + n] = val;
      }
    }
}

// ============================================================
// rf [H][HD][F] f32 -> rft [H][F][HD] f32 (contiguous wave-uniform rows)
// ============================================================
__global__ void rf_transpose(const float* __restrict__ rf, float* __restrict__ rft)
{
  const int h = blockIdx.x, d = blockIdx.y, f = threadIdx.x;
  rft[((size_t)h * Ff + f) * HDd + d] = rf[((size_t)(h * HDd + d)) * Ff + f];
}

// ============================================================
// Fused kv/ksum via MFMA. Replaces the VALU kv_ksum_v2 (1670us -> ~MFMA rate).
// Per (bh, s-split) block, loop 64-row s-chunks:
//   stage K [64s][64d] + Vt [64d][64s] in LDS (XOR-swizzled c^=(row&7));
//   P[s][f] = K @ rf  (MFMA, rf staged once as bf16 from f32 rft);
//   kp = softplus(P); ksum partials in regs; write P^T bf16 to per-wave LDS;
//   kv[f][d] += P^T @ Vt  (MFMA, f32 acc); epilogue f32 atomics.
// Wave w owns f-slice [w*64, w*64+64): P^T written+read by same wave only.
// LDS 80KB -> 2 blocks/CU. Swizzle write/read formulas verified identical:
//   write off = (row*128 + mi*32 + quad*8) ^ ((row&7)<<4)
//            == row*128 + ((2*mi + (quad>>1)) ^ (row&7))*16 + (quad&1)*8
//   read  off = row*128 + (((ks*4+quad) ^ (row&7))*16)
// ============================================================
#define NSPLIT 8
#define SCHUNKS (Ss / NSPLIT / 64)   // 8 chunks of 64 rows

__global__ __launch_bounds__(256, 2) void kv_fused(
    const u16* __restrict__ Km, const u16* __restrict__ Vt,
    const float* __restrict__ rft, float* __restrict__ kv, float* __restrict__ ksum)
{
  __shared__ __align__(16) u16 RF[Ff * 64];       // 32KB rf[h] bf16 [f][d] swizzled
  __shared__ __align__(16) u16 KS[64 * 64];       // 8KB  K chunk [s][d] swizzled
  __shared__ __align__(16) u16 VS[64 * 64];       // 8KB  Vt chunk [d][s] swizzled
  __shared__ __align__(16) u16 PT[4][64 * 64];    // 32KB per-wave P^T [f][s] swizzled

  const int bh = blockIdx.x;
  const int b = bh >> 4, h = bh & 15;
  const int s0 = blockIdx.y * (Ss / NSPLIT);
  const int tid = threadIdx.x;
  const int wave = tid >> 6, lane = tid & 63;
  const int quad = lane >> 4, lm = lane & 15;
  const int F0 = wave * 64;

  // stage rft[h] -> RF (f32 -> bf16 in flight), once per block
  {
    const float* rh = rft + (size_t)h * Ff * HDd;
#pragma unroll
    for (int i = 0; i < 8; i++) {
      int qq = tid + 256 * i;
      int r = qq >> 3, c = qq & 7;                 // row f, 8-elem chunk of d
      const float* src = rh + r * 64 + c * 8;
      float4 a = *reinterpret_cast<const float4*>(src);
      float4 e = *reinterpret_cast<const float4*>(src + 4);
      u32 w0 = (u32)f2b(a.x) | ((u32)f2b(a.y) << 16);
      u32 w1 = (u32)f2b(a.z) | ((u32)f2b(a.w) << 16);
      u32 w2 = (u32)f2b(e.x) | ((u32)f2b(e.y) << 16);
      u32 w3 = (u32)f2b(e.z) | ((u32)f2b(e.w) << 16);
      *reinterpret_cast<uint4*>((char*)RF + r * 128 + ((c ^ (r & 7)) * 16)) =
          make_uint4(w0, w1, w2, w3);
    }
  }

  f32x4 kvacc[4][4] = {};
  float kss[4] = {0.f, 0.f, 0.f, 0.f};

  for (int ch = 0; ch < SCHUNKS; ch++) {
    const int sc0 = s0 + ch * 64;
    // stage K chunk [64 s][64 d] and Vt chunk [64 d][64 s], swizzled
#pragma unroll
    for (int i = 0; i < 2; i++) {
      int qq = tid + 256 * i;                      // 512 chunks of 16B each
      int r = qq >> 3, c = qq & 7;
      uint4 kd = *reinterpret_cast<const uint4*>(
          Km + (size_t)(b * Ss + sc0 + r) * Dd + h * 64 + c * 8);
      *reinterpret_cast<uint4*>((char*)KS + r * 128 + ((c ^ (r & 7)) * 16)) = kd;
      uint4 vd = *reinterpret_cast<const uint4*>(
          Vt + (size_t)(h * 64 + r) * Mm + b * Ss + sc0 + c * 8);
      *reinterpret_cast<uint4*>((char*)VS + r * 128 + ((c ^ (r & 7)) * 16)) = vd;
    }
    __syncthreads();

    // stage 1: P[s 0..63][f F0..F0+63] = K @ rf^T   (K-dim = d = 64, 2 k-steps)
    f32x4 p[4][4] = {};
#pragma unroll
    for (int ks = 0; ks < 2; ks++) {
      bf16x8 af[4], bfr[4];
#pragma unroll
      for (int mi = 0; mi < 4; mi++) {
        int row = mi * 16 + lm;                    // s row
        af[mi] = *reinterpret_cast<const bf16x8*>(
            (char*)KS + row * 128 + (((ks * 4 + quad) ^ (row & 7)) * 16));
      }
#pragma unroll
      for (int ni = 0; ni < 4; ni++) {
        int row = ni * 16 + lm;                    // f row within slice; (F0+row)&7 == row&7
        bfr[ni] = *reinterpret_cast<const bf16x8*>(
            (char*)RF + (F0 + row) * 128 + (((ks * 4 + quad) ^ (row & 7)) * 16));
      }
#pragma unroll
      for (int mi = 0; mi < 4; mi++)
#pragma unroll
        for (int ni = 0; ni < 4; ni++)
          p[mi][ni] = __builtin_amdgcn_mfma_f32_16x16x32_bf16(af[mi], bfr[ni], p[mi][ni], 0, 0, 0);
    }

    // softplus + ksum partials + write P^T bf16 into this wave's PT slice
#pragma unroll
    for (int mi = 0; mi < 4; mi++)
#pragma unroll
      for (int ni = 0; ni < 4; ni++) {
        float v0 = sfast(p[mi][ni][0]);
        float v1 = sfast(p[mi][ni][1]);
        float v2 = sfast(p[mi][ni][2]);
        float v3 = sfast(p[mi][ni][3]);
        kss[ni] += (v0 + v1) + (v2 + v3);
        u32 w0 = (u32)f2b(v0) | ((u32)f2b(v1) << 16);
        u32 w1 = (u32)f2b(v2) | ((u32)f2b(v3) << 16);
        int row = ni * 16 + lm;                    // f row; s cols = mi*16+quad*4+rr
        int off = (row * 128 + mi * 32 + quad * 8) ^ ((row & 7) << 4);
        *reinterpret_cast<uint2*>((char*)&PT[wave][0] + off) = make_uint2(w0, w1);
      }

    // stage 2: kv[f][d] += P^T @ Vt   (K-dim = s = 64, 2 k-steps; own PT + shared VS)
#pragma unroll
    for (int ks = 0; ks < 2; ks++) {
      bf16x8 a2[4], b2[4];
#pragma unroll
      for (int mi = 0; mi < 4; mi++) {
        int row = mi * 16 + lm;                    // f row
        a2[mi] = *reinterpret_cast<const bf16x8*>(
            (char*)&PT[wave][0] + row * 128 + (((ks * 4 + quad) ^ (row & 7)) * 16));
      }
#pragma unroll
      for (int ni = 0; ni < 4; ni++) {
        int row = ni * 16 + lm;                    // d row
        b2[ni] = *reinterpret_cast<const bf16x8*>(
            (char*)VS + row * 128 + (((ks * 4 + quad) ^ (row & 7)) * 16));
      }
#pragma unroll
      for (int mi = 0; mi < 4; mi++)
#pragma unroll
        for (int ni = 0; ni < 4; ni++)
          kvacc[mi][ni] = __builtin_amdgcn_mfma_f32_16x16x32_bf16(a2[mi], b2[ni], kvacc[mi][ni], 0, 0, 0);
    }
    __syncthreads();   // before next chunk overwrites KS/VS
  }

  // epilogue: f32 atomics into kv[bh][f][d] and ksum[bh][f]
  float* kvp = kv + (size_t)bh * Ff * HDd;
#pragma unroll
  for (int mi = 0; mi < 4; mi++)
#pragma unroll
    for (int ni = 0; ni < 4; ni++)
#pragma unroll
      for (int rr = 0; rr < 4; rr++) {
        int f = F0 + mi * 16 + quad * 4 + rr;
        int d = ni * 16 + lm;
        atomicAdd(kvp + (size_t)f * HDd + d, kvacc[mi][ni][rr]);
      }
#pragma unroll
  for (int ni = 0; ni < 4; ni++) {
    float v = kss[ni];
    v += __shfl_xor(v, 16, 64);
    v += __shfl_xor(v, 32, 64);                    // all lanes now hold full column sum
    if (quad == 0) atomicAdd(ksum + (size_t)bh * Ff + F0 + ni * 16 + lm, v);
  }
}

// ============================================================
// attn[s][h*64+d] bf16 = (sum_f softplus(q·rf_f) * kv[f,d]) / (qp·ksum + 1e-8)
// Writes bf16 (feeds final MFMA GEMM); aliases dead xb region.
// ============================================================
__global__ __launch_bounds__(256, 2) void attn_kernel(
    const u16* __restrict__ Qm, const float* __restrict__ rft,
    const float* __restrict__ kv, const float* __restrict__ ksum,
    u16* __restrict__ attnb)
{
  const int bh = blockIdx.x;
  const int b = bh >> 4, h = bh & 15;
  const int s = blockIdx.y * 256 + threadIdx.x;

  const size_t base = (size_t)(b * Ss + s) * Dd + h * 64;
  const u32* qr = reinterpret_cast<const u32*>(Qm + base);
  float q[64];
#pragma unroll
  for (int i = 0; i < 32; i++) { u32 u = qr[i]; q[2 * i] = bflo(u); q[2 * i + 1] = bfhi(u); }

  float acc[64];
#pragma unroll
  for (int d = 0; d < 64; d++) acc[d] = 0.f;
  float den = 0.f;

  const float* rfh = rft + (size_t)h * Ff * HDd;
  const float* kvh = kv + (size_t)bh * Ff * HDd;
  const float* ksh = ksum + (size_t)bh * Ff;

  for (int fc = 0; fc < Ff; fc++) {
    const float* rc = rfh + fc * HDd;   // wave-uniform
    float p0 = 0.f, p1 = 0.f, p2 = 0.f, p3 = 0.f;
#pragma unroll
    for (int d = 0; d < 64; d += 4) {
      p0 += q[d] * rc[d];         p1 += q[d + 1] * rc[d + 1];
      p2 += q[d + 2] * rc[d + 2]; p3 += q[d + 3] * rc[d + 3];
    }
    float qp = softplusf((p0 + p1) + (p2 + p3));
    den += qp * ksh[fc];
    const float* kc = kvh + fc * HDd;   // wave-uniform
#pragma unroll
    for (int d = 0; d < 64; d++) acc[d] += qp * kc[d];
  }

  const float inv = 1.f / (den + 1e-8f);
  u32* op = reinterpret_cast<u32*>(attnb + base);
#pragma unroll
  for (int i = 0; i < 32; i++)
    op[i] = (u32)f2b(acc[2 * i] * inv) | ((u32)f2b(acc[2 * i + 1] * inv) << 16);
}

// ============================================================
extern "C" void kernel_launch(void* const* d_in, const int* in_sizes, int n_in,
                              void* d_out, int out_size, void* d_ws, size_t ws_size,
                              hipStream_t stream)
{
  const float* x  = (const float*)d_in[0];
  const float* Wq = (const float*)d_in[1];
  const float* bq = (const float*)d_in[2];
  const float* Wk = (const float*)d_in[3];
  const float* bk = (const float*)d_in[4];
  const float* Wv = (const float*)d_in[5];
  const float* bv = (const float*)d_in[6];
  const float* Wo = (const float*)d_in[7];
  const float* bo = (const float*)d_in[8];
  const float* rf = (const float*)d_in[9];

  // workspace (~147 MB, unchanged size). attn-bf16 ALIASES xb (dead after V^T GEMM).
  char* w = (char*)d_ws;
  u16* xb = (u16*)w;        w += (size_t)Mm * Dd * 2;               // 33.5 MB (also attn-bf16)
  u16* q  = (u16*)w;        w += (size_t)Mm * Dd * 2;               // 33.5 MB
  u16* k  = (u16*)w;        w += (size_t)Mm * Dd * 2;               // 33.5 MB
  u16* vt = (u16*)w;        w += (size_t)Mm * Dd * 2;               // 33.5 MB  V^T [1024][16384]
  u16* wqb = (u16*)w;       w += (size_t)Dd * Dd * 2;               // 2 MB
  u16* wkb = (u16*)w;       w += (size_t)Dd * Dd * 2;
  u16* wvb = (u16*)w;       w += (size_t)Dd * Dd * 2;
  u16* wob = (u16*)w;       w += (size_t)Dd * Dd * 2;
  float* kv = (float*)w;    w += (size_t)(Bb * Hh) * Ff * HDd * 4;  // 4.19 MB
  float* ks = (float*)w;    w += (size_t)(Bb * Hh) * Ff * 4;        // 64 KB
  float* rft = (float*)w;   w += (size_t)Hh * Ff * HDd * 4;         // 1.05 MB

  // f32 -> bf16 conversions
  cvt_bf16<<<(Mm * Dd / 8 + 255) / 256, 256, 0, stream>>>(x, xb, Mm * Dd);
  cvt_bf16<<<(Dd * Dd / 8 + 255) / 256, 256, 0, stream>>>(Wq, wqb, Dd * Dd);
  cvt_bf16<<<(Dd * Dd / 8 + 255) / 256, 256, 0, stream>>>(Wk, wkb, Dd * Dd);
  cvt_bf16<<<(Dd * Dd / 8 + 255) / 256, 256, 0, stream>>>(Wv, wvb, Dd * Dd);
  cvt_bf16<<<(Dd * Dd / 8 + 255) / 256, 256, 0, stream>>>(Wo, wob, Dd * Dd);

  const int nz = (Bb * Hh) * Ff * HDd + (Bb * Hh) * Ff;
  zero_f32<<<(nz + 255) / 256, 256, 0, stream>>>(kv, nz);
  rf_transpose<<<dim3(Hh, HDd), 256, 0, stream>>>(rf, rft);

  const dim3 gg(Mm / 128, Dd / 128);
  mfma_gemm_bt<u16, false><<<gg, 256, 0, stream>>>(xb, wqb, bq, q, Mm, Dd, Dd);
  mfma_gemm_bt<u16, false><<<gg, 256, 0, stream>>>(xb, wkb, bk, k, Mm, Dd, Dd);
  // V^T directly: C[d][m] = sum_k Wv[d][k] x[m][k] + bv[d]  (bias per-row)
  const dim3 gv(Dd / 128, Mm / 128);
  mfma_gemm_bt<u16, true><<<gv, 256, 0, stream>>>(wvb, xb, bv, vt, Dd, Mm, Dd);

  // fused MFMA kv/ksum (replaces VALU kv_ksum_v2)
  kv_fused<<<dim3(Bb * Hh, NSPLIT), 256, 0, stream>>>(k, vt, rft, kv, ks);

  attn_kernel<<<dim3(Bb * Hh, Ss / 256), 256, 0, stream>>>(q, rft, kv, ks, xb);

  // final projection: f32 output
  mfma_gemm_bt<float, false><<<gg, 256, 0, stream>>>(xb, wob, bo, (float*)d_out, Mm, Dd, Dd);
}

// Round 2
// 531.644 us; speedup vs baseline: 4.4184x; 1.7134x over previous
//
#include <hip/hip_runtime.h>
#include <math.h>

// Problem constants
#define Bb 4
#define Ss 4096
#define Dd 1024
#define Hh 16
#define Ff 256
#define HDd 64
#define Mm (Bb*Ss)          // 16384 rows

typedef unsigned int u32;
typedef unsigned short u16;

typedef __attribute__((ext_vector_type(8))) short bf16x8;   // 8 bf16 = 4 VGPRs
typedef __attribute__((ext_vector_type(4))) float f32x4;

// ---- bf16 helpers ----
__device__ __forceinline__ float bflo(u32 u){ union{u32 i; float f;} c; c.i = u << 16; return c.f; }
__device__ __forceinline__ float bfhi(u32 u){ union{u32 i; float f;} c; c.i = u & 0xffff0000u; return c.f; }
__device__ __forceinline__ u16 f2b(float f){
  union{float f; u32 i;} c; c.f = f;
  u32 x = c.i;
  return (u16)((x + 0x7fffu + ((x >> 16) & 1u)) >> 16);   // RNE
}
__device__ __forceinline__ float softplusf(float x){
  return fmaxf(x, 0.f) + log1pf(expf(-fabsf(x)));   // jax.nn.softplus, stable
}
// fast softplus for the MFMA paths (v_exp/v_log native; err << bf16 noise)
__device__ __forceinline__ float sfast(float x){
  return fmaxf(x, 0.f) + __logf(1.f + __expf(-fabsf(x)));
}

// ============================================================
// f32 -> bf16 elementwise (8 elems/thread, vectorized)
// ============================================================
__global__ void cvt_bf16(const float* __restrict__ in, u16* __restrict__ out, int n)
{
  int i = (blockIdx.x * 256 + threadIdx.x) * 8;
  if (i >= n) return;
  float4 a = *reinterpret_cast<const float4*>(in + i);
  float4 b = *reinterpret_cast<const float4*>(in + i + 4);
  u32 w0 = (u32)f2b(a.x) | ((u32)f2b(a.y) << 16);
  u32 w1 = (u32)f2b(a.z) | ((u32)f2b(a.w) << 16);
  u32 w2 = (u32)f2b(b.x) | ((u32)f2b(b.y) << 16);
  u32 w3 = (u32)f2b(b.z) | ((u32)f2b(b.w) << 16);
  *reinterpret_cast<uint4*>(out + i) = make_uint4(w0, w1, w2, w3);
}

// ============================================================
// zero-fill (ws is re-poisoned 0xAA each call)
// ============================================================
__global__ void zero_f32(float* __restrict__ p, int n)
{
  int i = blockIdx.x * 256 + threadIdx.x;
  if (i < n) p[i] = 0.f;
}

// ============================================================
// MFMA GEMM: C[M,N] = A[M,K](bf16) * W[N,K]^T(bf16) + bias
// OT = u16 (bf16 store) or float (f32 store).
// BROW: bias indexed by row m (for the V^T gemm) instead of col n.
// 128x128 tile, BK=32, 4 waves (2x2 of 64x64).
// Verified layouts (m89/m91/m120): A[m=lane&15][k=quad*8+j],
// B[k=quad*8+j][n=lane&15], D[row=quad*4+r][col=lane&15].
// ============================================================
template<typename OT, bool BROW>
__global__ __launch_bounds__(256, 2) void mfma_gemm_bt(
    const u16* __restrict__ A, const u16* __restrict__ W,
    const float* __restrict__ bias, OT* __restrict__ C,
    int M, int N, int K)
{
  // rows of 32 bf16 + 8 pad = 40 u16 (80 B): frag-read banks 2-way (free)
  __shared__ __align__(16) u16 As[128 * 40];
  __shared__ __align__(16) u16 Bs[128 * 40];

  const int tid = threadIdx.x;
  const int wave = tid >> 6, lane = tid & 63;
  const int quad = lane >> 4, lm = lane & 15;
  const int wm = (wave >> 1) * 64, wn = (wave & 1) * 64;
  const int m0 = blockIdx.x * 128, n0 = blockIdx.y * 128;

  f32x4 acc[4][4] = {};   // zero-init

  for (int k0 = 0; k0 < K; k0 += 32) {
#pragma unroll
    for (int i = 0; i < 2; i++) {
      int slot = tid + 256 * i;          // 512 slots: 128 rows x 4 col-groups
      int r = slot >> 2, cg = slot & 3;
      *reinterpret_cast<uint4*>(&As[r * 40 + cg * 8]) =
          *reinterpret_cast<const uint4*>(A + (size_t)(m0 + r) * K + k0 + cg * 8);
      *reinterpret_cast<uint4*>(&Bs[r * 40 + cg * 8]) =
          *reinterpret_cast<const uint4*>(W + (size_t)(n0 + r) * K + k0 + cg * 8);
    }
    __syncthreads();

    bf16x8 af[4], bf[4];
#pragma unroll
    for (int mi = 0; mi < 4; mi++)
      af[mi] = *reinterpret_cast<const bf16x8*>(&As[(wm + mi * 16 + lm) * 40 + quad * 8]);
#pragma unroll
    for (int ni = 0; ni < 4; ni++)
      bf[ni] = *reinterpret_cast<const bf16x8*>(&Bs[(wn + ni * 16 + lm) * 40 + quad * 8]);
#pragma unroll
    for (int mi = 0; mi < 4; mi++)
#pragma unroll
      for (int ni = 0; ni < 4; ni++)
        acc[mi][ni] = __builtin_amdgcn_mfma_f32_16x16x32_bf16(af[mi], bf[ni], acc[mi][ni], 0, 0, 0);
    __syncthreads();
  }

  // epilogue: lane l, reg r -> C[m0+wm+mi*16+quad*4+r][n0+wn+ni*16+lm]
#pragma unroll
  for (int mi = 0; mi < 4; mi++)
#pragma unroll
    for (int ni = 0; ni < 4; ni++) {
      const int n = n0 + wn + ni * 16 + lm;
      const float bvn = BROW ? 0.f : bias[n];
#pragma unroll
      for (int r = 0; r < 4; r++) {
        const int m = m0 + wm + mi * 16 + quad * 4 + r;
        const float val = acc[mi][ni][r] + (BROW ? bias[m] : bvn);
        if constexpr (sizeof(OT) == 2) ((u16*)C)[(size_t)m * N + n] = f2b(val);
        else                           ((float*)C)[(size_t)m * N + n] = val;
      }
    }
}

// ============================================================
// rf [H][HD][F] f32 -> rft [H][F][HD] f32 (contiguous wave-uniform rows)
// ============================================================
__global__ void rf_transpose(const float* __restrict__ rf, float* __restrict__ rft)
{
  const int h = blockIdx.x, d = blockIdx.y, f = threadIdx.x;
  rft[((size_t)h * Ff + f) * HDd + d] = rf[((size_t)(h * HDd + d)) * Ff + f];
}

// ============================================================
// Fused kv/ksum via MFMA (round-1, verified).
// ============================================================
#define NSPLIT 8
#define SCHUNKS (Ss / NSPLIT / 64)   // 8 chunks of 64 rows

__global__ __launch_bounds__(256, 2) void kv_fused(
    const u16* __restrict__ Km, const u16* __restrict__ Vt,
    const float* __restrict__ rft, float* __restrict__ kv, float* __restrict__ ksum)
{
  __shared__ __align__(16) u16 RF[Ff * 64];       // 32KB rf[h] bf16 [f][d] swizzled
  __shared__ __align__(16) u16 KS[64 * 64];       // 8KB  K chunk [s][d] swizzled
  __shared__ __align__(16) u16 VS[64 * 64];       // 8KB  Vt chunk [d][s] swizzled
  __shared__ __align__(16) u16 PT[4][64 * 64];    // 32KB per-wave P^T [f][s] swizzled

  const int bh = blockIdx.x;
  const int b = bh >> 4, h = bh & 15;
  const int s0 = blockIdx.y * (Ss / NSPLIT);
  const int tid = threadIdx.x;
  const int wave = tid >> 6, lane = tid & 63;
  const int quad = lane >> 4, lm = lane & 15;
  const int F0 = wave * 64;

  // stage rft[h] -> RF (f32 -> bf16 in flight), once per block
  {
    const float* rh = rft + (size_t)h * Ff * HDd;
#pragma unroll
    for (int i = 0; i < 8; i++) {
      int qq = tid + 256 * i;
      int r = qq >> 3, c = qq & 7;                 // row f, 8-elem chunk of d
      const float* src = rh + r * 64 + c * 8;
      float4 a = *reinterpret_cast<const float4*>(src);
      float4 e = *reinterpret_cast<const float4*>(src + 4);
      u32 w0 = (u32)f2b(a.x) | ((u32)f2b(a.y) << 16);
      u32 w1 = (u32)f2b(a.z) | ((u32)f2b(a.w) << 16);
      u32 w2 = (u32)f2b(e.x) | ((u32)f2b(e.y) << 16);
      u32 w3 = (u32)f2b(e.z) | ((u32)f2b(e.w) << 16);
      *reinterpret_cast<uint4*>((char*)RF + r * 128 + ((c ^ (r & 7)) * 16)) =
          make_uint4(w0, w1, w2, w3);
    }
  }

  f32x4 kvacc[4][4] = {};
  float kss[4] = {0.f, 0.f, 0.f, 0.f};

  for (int ch = 0; ch < SCHUNKS; ch++) {
    const int sc0 = s0 + ch * 64;
    // stage K chunk [64 s][64 d] and Vt chunk [64 d][64 s], swizzled
#pragma unroll
    for (int i = 0; i < 2; i++) {
      int qq = tid + 256 * i;                      // 512 chunks of 16B each
      int r = qq >> 3, c = qq & 7;
      uint4 kd = *reinterpret_cast<const uint4*>(
          Km + (size_t)(b * Ss + sc0 + r) * Dd + h * 64 + c * 8);
      *reinterpret_cast<uint4*>((char*)KS + r * 128 + ((c ^ (r & 7)) * 16)) = kd;
      uint4 vd = *reinterpret_cast<const uint4*>(
          Vt + (size_t)(h * 64 + r) * Mm + b * Ss + sc0 + c * 8);
      *reinterpret_cast<uint4*>((char*)VS + r * 128 + ((c ^ (r & 7)) * 16)) = vd;
    }
    __syncthreads();

    // stage 1: P[s 0..63][f F0..F0+63] = K @ rf^T   (K-dim = d = 64, 2 k-steps)
    f32x4 p[4][4] = {};
#pragma unroll
    for (int ks = 0; ks < 2; ks++) {
      bf16x8 af[4], bfr[4];
#pragma unroll
      for (int mi = 0; mi < 4; mi++) {
        int row = mi * 16 + lm;                    // s row
        af[mi] = *reinterpret_cast<const bf16x8*>(
            (char*)KS + row * 128 + (((ks * 4 + quad) ^ (row & 7)) * 16));
      }
#pragma unroll
      for (int ni = 0; ni < 4; ni++) {
        int row = ni * 16 + lm;                    // f row within slice
        bfr[ni] = *reinterpret_cast<const bf16x8*>(
            (char*)RF + (F0 + row) * 128 + (((ks * 4 + quad) ^ (row & 7)) * 16));
      }
#pragma unroll
      for (int mi = 0; mi < 4; mi++)
#pragma unroll
        for (int ni = 0; ni < 4; ni++)
          p[mi][ni] = __builtin_amdgcn_mfma_f32_16x16x32_bf16(af[mi], bfr[ni], p[mi][ni], 0, 0, 0);
    }

    // softplus + ksum partials + write P^T bf16 into this wave's PT slice
#pragma unroll
    for (int mi = 0; mi < 4; mi++)
#pragma unroll
      for (int ni = 0; ni < 4; ni++) {
        float v0 = sfast(p[mi][ni][0]);
        float v1 = sfast(p[mi][ni][1]);
        float v2 = sfast(p[mi][ni][2]);
        float v3 = sfast(p[mi][ni][3]);
        kss[ni] += (v0 + v1) + (v2 + v3);
        u32 w0 = (u32)f2b(v0) | ((u32)f2b(v1) << 16);
        u32 w1 = (u32)f2b(v2) | ((u32)f2b(v3) << 16);
        int row = ni * 16 + lm;                    // f row; s cols = mi*16+quad*4+rr
        int off = (row * 128 + mi * 32 + quad * 8) ^ ((row & 7) << 4);
        *reinterpret_cast<uint2*>((char*)&PT[wave][0] + off) = make_uint2(w0, w1);
      }

    // stage 2: kv[f][d] += P^T @ Vt   (K-dim = s = 64, 2 k-steps; own PT + shared VS)
#pragma unroll
    for (int ks = 0; ks < 2; ks++) {
      bf16x8 a2[4], b2[4];
#pragma unroll
      for (int mi = 0; mi < 4; mi++) {
        int row = mi * 16 + lm;                    // f row
        a2[mi] = *reinterpret_cast<const bf16x8*>(
            (char*)&PT[wave][0] + row * 128 + (((ks * 4 + quad) ^ (row & 7)) * 16));
      }
#pragma unroll
      for (int ni = 0; ni < 4; ni++) {
        int row = ni * 16 + lm;                    // d row
        b2[ni] = *reinterpret_cast<const bf16x8*>(
            (char*)VS + row * 128 + (((ks * 4 + quad) ^ (row & 7)) * 16));
      }
#pragma unroll
      for (int mi = 0; mi < 4; mi++)
#pragma unroll
        for (int ni = 0; ni < 4; ni++)
          kvacc[mi][ni] = __builtin_amdgcn_mfma_f32_16x16x32_bf16(a2[mi], b2[ni], kvacc[mi][ni], 0, 0, 0);
    }
    __syncthreads();   // before next chunk overwrites KS/VS
  }

  // epilogue: f32 atomics into kv[bh][f][d] and ksum[bh][f]
  float* kvp = kv + (size_t)bh * Ff * HDd;
#pragma unroll
  for (int mi = 0; mi < 4; mi++)
#pragma unroll
    for (int ni = 0; ni < 4; ni++)
#pragma unroll
      for (int rr = 0; rr < 4; rr++) {
        int f = F0 + mi * 16 + quad * 4 + rr;
        int d = ni * 16 + lm;
        atomicAdd(kvp + (size_t)f * HDd + d, kvacc[mi][ni][rr]);
      }
#pragma unroll
  for (int ni = 0; ni < 4; ni++) {
    float v = kss[ni];
    v += __shfl_xor(v, 16, 64);
    v += __shfl_xor(v, 32, 64);
    if (quad == 0) atomicAdd(ksum + (size_t)bh * Ff + F0 + ni * 16 + lm, v);
  }
}

// ============================================================
// kv f32 [bh][f=256][d=64] -> kvT bf16 [bh][d=64][f=256]
// grid 64 (bh), 256 thr: thread = (d = t&63, fgrp = t>>6), 64 f each.
// Reads are strided f32 (L2-resident, 4MB); writes 128B contiguous.
// ============================================================
__global__ void kvt_cvt(const float* __restrict__ kv, u16* __restrict__ kvtb)
{
  const int bh = blockIdx.x;
  const int d = threadIdx.x & 63, fg = threadIdx.x >> 6;
  const float* src = kv + (size_t)bh * Ff * HDd + d;
  u32* dst = reinterpret_cast<u32*>(kvtb + (size_t)bh * HDd * Ff + (size_t)d * Ff + fg * 64);
#pragma unroll
  for (int j = 0; j < 32; j++) {
    float v0 = src[(size_t)(fg * 64 + 2 * j) * HDd];
    float v1 = src[(size_t)(fg * 64 + 2 * j + 1) * HDd];
    dst[j] = (u32)f2b(v0) | ((u32)f2b(v1) << 16);
  }
}

// ============================================================
// Fused attention via MFMA (replaces VALU attn_kernel, 543us).
// Per (bh, s-split of 512) block, 8 chunks of 64 s-rows, 4 waves.
// Block-constant REGISTER operands: rf B-frags (bfr, 32 VGPR),
// kvT B-frags (b2r, 32 VGPR), ksum (4).
// Per chunk:
//   stage1: Q frags direct from global (read-once) -> P = Q @ rf^T (32 MFMA)
//   softplus + bf16-round; den partials use the SAME rounded qp as numerator;
//   pair-pack (shfl_xor 1) -> u32 writes into P4[wave] (XOR-swizzled, 2-way-free);
//   den: shfl-reduce over lm, lm==0 writes den4[s][wave];
//   barrier; stage2: attn[s][d-slice16/wave] = P @ kvT (32 b128 + 32 MFMA);
//   den read (float4 sum of 4 wave partials + 1e-8), divide, bf16 store; barrier.
// LDS 33.8KB -> 2 blocks/CU.
// ============================================================
__global__ __launch_bounds__(256, 2) void attn_fused(
    const u16* __restrict__ Qm, const float* __restrict__ rft,
    const u16* __restrict__ kvtb, const float* __restrict__ ksum,
    u16* __restrict__ attnb)
{
  __shared__ __align__(16) u16 P4[4][64 * 64];    // 32KB [fb][s][f'] swizzled
  __shared__ __align__(16) float den4[64][4];     // [s][wave] partial denominators

  const int bh = blockIdx.x;
  const int b = bh >> 4, h = bh & 15;
  const int s0 = blockIdx.y * (Ss / NSPLIT);
  const int tid = threadIdx.x;
  const int wave = tid >> 6, lane = tid & 63;
  const int quad = lane >> 4, lm = lane & 15;
  const int F0 = wave * 64;

  // rf fragments (stage-1 B operand): rft[h][F0+ni*16+lm][ks*32+quad*8 ..+8]
  bf16x8 bfr[4][2];
  {
    const float* rh = rft + (size_t)h * Ff * HDd;
#pragma unroll
    for (int ni = 0; ni < 4; ni++) {
      const float* rrow = rh + (size_t)(F0 + ni * 16 + lm) * HDd;
#pragma unroll
      for (int ks = 0; ks < 2; ks++) {
        float4 a = *reinterpret_cast<const float4*>(rrow + ks * 32 + quad * 8);
        float4 e = *reinterpret_cast<const float4*>(rrow + ks * 32 + quad * 8 + 4);
        union { u16 a[8]; bf16x8 v; } u;
        u.a[0] = f2b(a.x); u.a[1] = f2b(a.y); u.a[2] = f2b(a.z); u.a[3] = f2b(a.w);
        u.a[4] = f2b(e.x); u.a[5] = f2b(e.y); u.a[6] = f2b(e.z); u.a[7] = f2b(e.w);
        bfr[ni][ks] = u.v;
      }
    }
  }
  // kvT fragments (stage-2 B operand): kvtb[bh][wave*16+lm][fb*64+k2*32+quad*8 ..+8]
  bf16x8 b2r[4][2];
  {
    const u16* kb = kvtb + (size_t)bh * HDd * Ff + (size_t)(wave * 16 + lm) * Ff;
#pragma unroll
    for (int fb = 0; fb < 4; fb++)
#pragma unroll
      for (int k2 = 0; k2 < 2; k2++)
        b2r[fb][k2] = *reinterpret_cast<const bf16x8*>(kb + fb * 64 + k2 * 32 + quad * 8);
  }
  // ksum per lane (f = F0 + ni*16 + lm)
  float ksv[4];
#pragma unroll
  for (int ni = 0; ni < 4; ni++)
    ksv[ni] = ksum[(size_t)bh * Ff + F0 + ni * 16 + lm];

  for (int ch = 0; ch < SCHUNKS; ch++) {
    const int sc0 = s0 + ch * 64;

    // stage 1: Q fragments direct from global (coalesced 64B rows), MFMA
    bf16x8 af[4][2];
#pragma unroll
    for (int mi = 0; mi < 4; mi++) {
      const u16* qrow = Qm + (size_t)(b * Ss + sc0 + mi * 16 + lm) * Dd + h * 64;
#pragma unroll
      for (int ks = 0; ks < 2; ks++)
        af[mi][ks] = *reinterpret_cast<const bf16x8*>(qrow + ks * 32 + quad * 8);
    }
    f32x4 p[4][4] = {};
#pragma unroll
    for (int ks = 0; ks < 2; ks++)
#pragma unroll
      for (int mi = 0; mi < 4; mi++)
#pragma unroll
        for (int ni = 0; ni < 4; ni++)
          p[mi][ni] = __builtin_amdgcn_mfma_f32_16x16x32_bf16(af[mi][ks], bfr[ni][ks], p[mi][ni], 0, 0, 0);

    // softplus + round + den partials + pair-pack + P4 write
#pragma unroll
    for (int mi = 0; mi < 4; mi++) {
      const int sbase = mi * 16 + quad * 4;
      float dd[4] = {0.f, 0.f, 0.f, 0.f};
#pragma unroll
      for (int ni = 0; ni < 4; ni++) {
        u16 bq[4];
#pragma unroll
        for (int r = 0; r < 4; r++) {
          float v = sfast(p[mi][ni][r]);
          bq[r] = f2b(v);
          dd[r] += bflo((u32)bq[r]) * ksv[ni];   // den from ROUNDED qp (matches numerator)
        }
        int ob0 = __shfl_xor((int)(u32)bq[0], 1, 64);
        int ob1 = __shfl_xor((int)(u32)bq[1], 1, 64);
        int ob2 = __shfl_xor((int)(u32)bq[2], 1, 64);
        int ob3 = __shfl_xor((int)(u32)bq[3], 1, 64);
        const int odd = lm & 1;
        // even lane writes rr=0,1 pairs; odd lane writes rr=2,3 pairs (f'base = lm&~1)
        u32 w_a = odd ? ((u32)(u16)ob2 | ((u32)bq[2] << 16)) : ((u32)bq[0] | ((u32)(u16)ob0 << 16));
        u32 w_b = odd ? ((u32)(u16)ob3 | ((u32)bq[3] << 16)) : ((u32)bq[1] | ((u32)(u16)ob1 << 16));
        const int row_a = sbase + (odd ? 2 : 0);
        const int row_b = sbase + (odd ? 3 : 1);
        const int fpb = ni * 16 + (lm & ~1);
        const int cc = fpb >> 3;
        const int bib = (fpb & 7) * 2;
        *reinterpret_cast<u32*>((char*)&P4[wave][0] + row_a * 128 + ((cc ^ (row_a & 7)) << 4) + bib) = w_a;
        *reinterpret_cast<u32*>((char*)&P4[wave][0] + row_b * 128 + ((cc ^ (row_b & 7)) << 4) + bib) = w_b;
      }
      // reduce den partials over lm (16-lane groups), write per-wave partial
#pragma unroll
      for (int r = 0; r < 4; r++) {
        float v = dd[r];
        v += __shfl_xor(v, 1, 64);
        v += __shfl_xor(v, 2, 64);
        v += __shfl_xor(v, 4, 64);
        v += __shfl_xor(v, 8, 64);
        if (lm == 0) den4[sbase + r][wave] = v;
      }
    }
    __syncthreads();   // P4 + den4 complete

    // stage 2: attn[s][d] = P @ kvT, waves split by 16-wide d-slices
    f32x4 acc2[4] = {};
#pragma unroll
    for (int fb = 0; fb < 4; fb++)
#pragma unroll
      for (int k2 = 0; k2 < 2; k2++) {
        bf16x8 af2[4];
#pragma unroll
        for (int mi = 0; mi < 4; mi++) {
          int row = mi * 16 + lm;                  // s row
          af2[mi] = *reinterpret_cast<const bf16x8*>(
              (char*)&P4[fb][0] + row * 128 + (((k2 * 4 + quad) ^ (row & 7)) << 4));
        }
#pragma unroll
        for (int mi = 0; mi < 4; mi++)
          acc2[mi] = __builtin_amdgcn_mfma_f32_16x16x32_bf16(af2[mi], b2r[fb][k2], acc2[mi], 0, 0, 0);
      }

    // divide by den, bf16 store: out[s = mi*16+quad*4+r][d = wave*16+lm]
#pragma unroll
    for (int mi = 0; mi < 4; mi++) {
#pragma unroll
      for (int r = 0; r < 4; r++) {
        const int s = mi * 16 + quad * 4 + r;
        float4 dv = *reinterpret_cast<const float4*>(&den4[s][0]);
        const float inv = 1.f / ((dv.x + dv.y) + (dv.z + dv.w) + 1e-8f);
        attnb[(size_t)(b * Ss + sc0 + s) * Dd + h * 64 + wave * 16 + lm] =
            f2b(acc2[mi][r] * inv);
      }
    }
    __syncthreads();   // before next chunk overwrites P4/den4
  }
}

// ============================================================
extern "C" void kernel_launch(void* const* d_in, const int* in_sizes, int n_in,
                              void* d_out, int out_size, void* d_ws, size_t ws_size,
                              hipStream_t stream)
{
  const float* x  = (const float*)d_in[0];
  const float* Wq = (const float*)d_in[1];
  const float* bq = (const float*)d_in[2];
  const float* Wk = (const float*)d_in[3];
  const float* bk = (const float*)d_in[4];
  const float* Wv = (const float*)d_in[5];
  const float* bv = (const float*)d_in[6];
  const float* Wo = (const float*)d_in[7];
  const float* bo = (const float*)d_in[8];
  const float* rf = (const float*)d_in[9];

  // workspace (~147 MB). attn-bf16 ALIASES xb (dead after V^T GEMM);
  // kvT-bf16 ALIASES wqb (dead after Q GEMM).
  char* w = (char*)d_ws;
  u16* xb = (u16*)w;        w += (size_t)Mm * Dd * 2;               // 33.5 MB (also attn-bf16)
  u16* q  = (u16*)w;        w += (size_t)Mm * Dd * 2;               // 33.5 MB
  u16* k  = (u16*)w;        w += (size_t)Mm * Dd * 2;               // 33.5 MB
  u16* vt = (u16*)w;        w += (size_t)Mm * Dd * 2;               // 33.5 MB  V^T [1024][16384]
  u16* wqb = (u16*)w;       w += (size_t)Dd * Dd * 2;               // 2 MB (also kvT bf16)
  u16* wkb = (u16*)w;       w += (size_t)Dd * Dd * 2;
  u16* wvb = (u16*)w;       w += (size_t)Dd * Dd * 2;
  u16* wob = (u16*)w;       w += (size_t)Dd * Dd * 2;
  float* kv = (float*)w;    w += (size_t)(Bb * Hh) * Ff * HDd * 4;  // 4.19 MB
  float* ks = (float*)w;    w += (size_t)(Bb * Hh) * Ff * 4;        // 64 KB
  float* rft = (float*)w;   w += (size_t)Hh * Ff * HDd * 4;         // 1.05 MB
  u16* kvtb = wqb;          // 2 MB alias: kvT bf16 [bh][d][f]

  // f32 -> bf16 conversions
  cvt_bf16<<<(Mm * Dd / 8 + 255) / 256, 256, 0, stream>>>(x, xb, Mm * Dd);
  cvt_bf16<<<(Dd * Dd / 8 + 255) / 256, 256, 0, stream>>>(Wq, wqb, Dd * Dd);
  cvt_bf16<<<(Dd * Dd / 8 + 255) / 256, 256, 0, stream>>>(Wk, wkb, Dd * Dd);
  cvt_bf16<<<(Dd * Dd / 8 + 255) / 256, 256, 0, stream>>>(Wv, wvb, Dd * Dd);
  cvt_bf16<<<(Dd * Dd / 8 + 255) / 256, 256, 0, stream>>>(Wo, wob, Dd * Dd);

  const int nz = (Bb * Hh) * Ff * HDd + (Bb * Hh) * Ff;
  zero_f32<<<(nz + 255) / 256, 256, 0, stream>>>(kv, nz);
  rf_transpose<<<dim3(Hh, HDd), 256, 0, stream>>>(rf, rft);

  const dim3 gg(Mm / 128, Dd / 128);
  mfma_gemm_bt<u16, false><<<gg, 256, 0, stream>>>(xb, wqb, bq, q, Mm, Dd, Dd);
  mfma_gemm_bt<u16, false><<<gg, 256, 0, stream>>>(xb, wkb, bk, k, Mm, Dd, Dd);
  // V^T directly: C[d][m] = sum_k Wv[d][k] x[m][k] + bv[d]  (bias per-row)
  const dim3 gv(Dd / 128, Mm / 128);
  mfma_gemm_bt<u16, true><<<gv, 256, 0, stream>>>(wvb, xb, bv, vt, Dd, Mm, Dd);

  // fused MFMA kv/ksum
  kv_fused<<<dim3(Bb * Hh, NSPLIT), 256, 0, stream>>>(k, vt, rft, kv, ks);

  // kv -> kvT bf16 (into dead wqb region)
  kvt_cvt<<<Bb * Hh, 256, 0, stream>>>(kv, kvtb);

  // fused MFMA attention (writes bf16 into dead xb region)
  attn_fused<<<dim3(Bb * Hh, NSPLIT), 256, 0, stream>>>(q, rft, kvtb, ks, xb);

  // final projection: f32 output
  mfma_gemm_bt<float, false><<<gg, 256, 0, stream>>>(xb, wob, bo, (float*)d_out, Mm, Dd, Dd);
}